// Round 7
// baseline (254.295 us; speedup 1.0000x reference)
//
#include <hip/hip_runtime.h>

#define HH 512
#define WW 512
#define PD 544                          // 512 + 2*16
#define PADN (3 * PD * PD)              // padded fp32 elements (3 channels)
#define OUTN (3 * HH * WW)
#define NB 128
#define KSTR 16384                      // 128*128 floats between taps

typedef float f2 __attribute__((ext_vector_type(2)));

// ---------------- pad + out-zero: fp32 img -> fp32 edge-padded ----------------
__global__ __launch_bounds__(256) void pad_f32(const float* __restrict__ img,
                                               float* __restrict__ gpad,
                                               float* __restrict__ out) {
    int idx = blockIdx.x * 256 + threadIdx.x;
    if (idx < OUTN) out[idx] = 0.0f;           // zero the atomic target
    if (idx >= PADN) return;
    int c  = idx / (PD * PD);
    int r  = idx - c * (PD * PD);
    int py = r / PD;
    int px = r - py * PD;
    int iy = min(max(py - 16, 0), HH - 1);
    int ix = min(max(px - 16, 0), WW - 1);
    gpad[idx] = img[(c * HH + iy) * WW + ix];
}

// ---------------- main kernel: direct, LDS-free, big-granule weights --------
// ROUND 13: CHANGE THE ACCESS PATTERN, NOT THE SCHEDULE. Rounds 0-6: six
// structurally different schedules (barrier/no-barrier, 2/4 blk/CU, weight
// reg-dbuf/single/LDS-async, bf16/fp32, VALU cut 40%) ALL tie at 63-68us.
// Invariant: weights fetched in 256B granules at 64KB stride (64 lanes x 4B
// of one [h][w] row per tap). Measured 1.45 TB/s with ~9MB in flight =>
// ~15k-cy effective latency => memory system is SERVICE-RATE saturated for
// this pattern; scheduling cannot help. Fix:
//  - block = (uq, hq), 1024 thr (16 waves = 4/SIMD), covers 4 h x 128 w
//    (16 out rows x 512 cols x 3c). Per tap the block reads
//    K[uv][4hq..4hq+3][0..127] = 2 KB CONTIGUOUS (8x bigger granule).
//  - wave = out row, lane = w (2 halves of 64). Lane loads exactly the
//    weights it consumes (4-wave redundancy served by L1/L2).
//  - image windows (36 cols, 16B-aligned) read DIRECTLY from the
//    L2-resident fp32 pad buffer (3.5 MB): 9x dwordx4 per (u,c,half).
//    NO LDS, NO barriers, NO async counting anywhere.
//  - 8 u-chunks (5+4x7) -> grid 256 = exactly 1 block/CU. uq-major block
//    index => all 8 atomic partners of an hq land on XCD hq%8 (b%8), so
//    atomicAdd lines coalesce in one XCD's L2.
// Per thread: acc 24 (12 f2) + wv[33] + wf[36] ~ 110 VGPR, fits the 128 cap.
__global__ __launch_bounds__(1024, 2) void reblur_direct(const float* __restrict__ gpad,
                                                         const float* __restrict__ Kern,
                                                         float* __restrict__ out) {
    const int tid  = threadIdx.x;
    const int lane = tid & 63;
    const int w16  = tid >> 6;                 // wave 0..15 = row-within-tile
    const int b    = blockIdx.x;               // uq*32 + hq  (uq-major!)
    const int uq   = b >> 5;                   // 0..7
    const int hq   = b & 31;                   // 0..31
    const int orow = 16 * hq + w16;            // output row 0..511
    const int h    = orow >> 2;                // kernel-grid row
    const int u0   = uq ? (4 * uq + 1) : 0;    // chunk taps: 5,4,4,4,4,4,4,4
    const int nu   = uq ? 4 : 5;

    f2 aL[3][2], aH[3][2];                     // [c][half]: (oj0,oj1)/(oj2,oj3)
#pragma unroll
    for (int c = 0; c < 3; ++c)
#pragma unroll
        for (int hf = 0; hf < 2; ++hf) { aL[c][hf] = (f2)(0.0f); aH[c][hf] = (f2)(0.0f); }

#pragma unroll 1
    for (int t = 0; t < nu; ++t) {
        const int u = u0 + t;
        const size_t krow = (size_t)(u * 33) * KSTR + (size_t)h * NB;
#pragma unroll
        for (int hf = 0; hf < 2; ++hf) {
            const int w = hf * 64 + lane;      // kernel-grid col 0..127
            // 33 taps' weights for (h,w): block-level footprint per tap is
            // 4 rows x 512B = 2KB contiguous -> DRAM/L3-friendly granules
            float wv[33];
#pragma unroll
            for (int v = 0; v < 33; ++v)
                wv[v] = Kern[krow + (size_t)v * KSTR + w];
#pragma unroll
            for (int c = 0; c < 3; ++c) {
                // 36-col fp32 window at pad row orow+u, col 4w (16B aligned)
                const float* ip = gpad + ((size_t)c * PD + orow + u) * PD + 4 * w;
                float wf[36];
#pragma unroll
                for (int j = 0; j < 9; ++j) {
                    const float4 rr = *(const float4*)(ip + 4 * j);
                    wf[4 * j + 0] = rr.x;
                    wf[4 * j + 1] = rr.y;
                    wf[4 * j + 2] = rr.z;
                    wf[4 * j + 3] = rr.w;
                }
                f2 l = aL[c][hf], hh = aH[c][hf];
#pragma unroll
                for (int v = 0; v < 33; ++v) {
                    const f2 w2 = {wv[v], wv[v]};
                    const f2 xl = {wf[v + 0], wf[v + 1]};
                    const f2 xh = {wf[v + 2], wf[v + 3]};
                    l  = xl * w2 + l;          // -> v_pk_fma_f32
                    hh = xh * w2 + hh;
                }
                aL[c][hf] = l; aH[c][hf] = hh;
            }
        }
    }

    // ---- epilogue: 8 u-chunks accumulate into the pad-zeroed output ----
#pragma unroll
    for (int c = 0; c < 3; ++c) {
        float* orow_p = out + ((size_t)c * HH + orow) * WW;
#pragma unroll
        for (int hf = 0; hf < 2; ++hf) {
            float* op = orow_p + 4 * (hf * 64 + lane);
            atomicAdd(op + 0, aL[c][hf].x);
            atomicAdd(op + 1, aL[c][hf].y);
            atomicAdd(op + 2, aH[c][hf].x);
            atomicAdd(op + 3, aH[c][hf].y);
        }
    }
}

// ---------------- fallback (ws too small): naive but correct ----------------
__global__ __launch_bounds__(256) void reblur_naive(const float* __restrict__ img,
                                                    const float* __restrict__ Kern,
                                                    float* __restrict__ out) {
    const int lane = threadIdx.x & 63;
    const int dy   = threadIdx.x >> 6;
    const int c    = blockIdx.x >> 8;
    const int bb   = blockIdx.x & 255;
    const int h    = bb >> 1;
    const int wt   = bb & 1;
    const int wb   = wt * 64 + lane;
    const int y    = 4 * h + dy;

    float acc[4] = {0.f, 0.f, 0.f, 0.f};
    const float* kb = Kern + h * NB + wb;
#pragma unroll 1
    for (int u = 0; u < 33; ++u) {
        const int iy = min(max(y + u - 16, 0), HH - 1);
        float row[36];
#pragma unroll
        for (int e = 0; e < 36; ++e) {
            const int ix = min(max(4 * wb + e - 16, 0), WW - 1);
            row[e]       = img[(c * HH + iy) * WW + ix];
        }
#pragma unroll
        for (int v = 0; v < 33; ++v) {
            const float w = kb[(u * 33 + v) * KSTR];
#pragma unroll
            for (int oj = 0; oj < 4; ++oj)
                acc[oj] = fmaf(row[v + oj], w, acc[oj]);
        }
    }
    float4 o;
    o.x = acc[0]; o.y = acc[1]; o.z = acc[2]; o.w = acc[3];
    *reinterpret_cast<float4*>(out + (size_t)(c * HH + y) * WW + 4 * wb) = o;
}

extern "C" void kernel_launch(void* const* d_in, const int* in_sizes, int n_in,
                              void* d_out, int out_size, void* d_ws, size_t ws_size,
                              hipStream_t stream) {
    const float* img  = (const float*)d_in[0];
    const float* Kern = (const float*)d_in[1];
    float* out        = (float*)d_out;

    if (ws_size >= (size_t)PADN * sizeof(float)) {
        float* gpad = (float*)d_ws;
        pad_f32<<<(PADN + 255) / 256, 256, 0, stream>>>(img, gpad, out);
        reblur_direct<<<256, 1024, 0, stream>>>(gpad, Kern, out);
    } else {
        reblur_naive<<<768, 256, 0, stream>>>(img, Kern, out);
    }
}

// Round 8
// 250.022 us; speedup vs baseline: 1.0171x; 1.0171x over previous
//
#include <hip/hip_runtime.h>

#define HH 512
#define WW 512
#define PD 544                          // 512 + 2*16
#define PADN (3 * PD * PD)              // padded fp32 elements (3 channels)
#define OUTN (3 * HH * WW)
#define NB 128
#define KSTR 16384                      // 128*128 floats between taps

typedef float f2 __attribute__((ext_vector_type(2)));

// ---------------- pad + out-zero: fp32 img -> fp32 edge-padded ----------------
__global__ __launch_bounds__(256) void pad_f32(const float* __restrict__ img,
                                               float* __restrict__ gpad,
                                               float* __restrict__ out) {
    int idx = blockIdx.x * 256 + threadIdx.x;
    if (idx < OUTN) out[idx] = 0.0f;           // zero the atomic target
    if (idx >= PADN) return;
    int c  = idx / (PD * PD);
    int r  = idx - c * (PD * PD);
    int py = r / PD;
    int px = r - py * PD;
    int iy = min(max(py - 16, 0), HH - 1);
    int ix = min(max(px - 16, 0), WW - 1);
    gpad[idx] = img[(c * HH + iy) * WW + ix];
}

// ---------------- main kernel: direct, LDS-free, big-granule weights --------
// ROUND 14: SAME STRUCTURE AS ROUND 13, FIXED REGISTER BUDGET.
// ROUND-13 LESSON: __launch_bounds__(1024,2) = 16 waves x 2 blocks/CU =
// 8 waves/SIMD -> VGPR cap 512/8 = 64 < ~110 live set -> inner-loop scratch
// spill (WRITE 134MB, VALUBusy 9%, 170us). The 2KB-granule access-pattern
// theory was never tested. Fix: __launch_bounds__(1024,1) -> 1 block/CU
// (matches the 256-block grid exactly) = 4 waves/SIMD -> VGPR cap 128,
// live set fits, occupancy unchanged from what round 13 actually ran at.
//
// Theory under test (from rounds 0-6): six different schedules all tie at
// 63-68us because weights were fetched in 256B granules at 64KB stride --
// service-rate saturation, not latency. This decomposition reads
// K[uv][4hq..4hq+3][0..127] = 2KB CONTIGUOUS per (block, tap):
//  - block = (uq, hq), 1024 thr (16 waves = 4/SIMD), covers 16 out rows
//    x 512 cols x 3c. wave = out row, lane = w (2 halves of 64).
//  - lane loads exactly the weights it consumes (4-wave redundancy L1/L2).
//  - image windows (36 cols, 16B-aligned) read DIRECTLY from the
//    L2-resident fp32 pad buffer: 9x dwordx4 per (u,c,half). NO LDS,
//    NO barriers, NO async counting.
//  - 8 u-chunks (5+4x7) -> grid 256 = 1 block/CU. uq-major block index =>
//    all 8 atomic partners of an hq land on the same XCD (b%8 = hq%8).
__global__ __launch_bounds__(1024, 1) void reblur_direct(const float* __restrict__ gpad,
                                                         const float* __restrict__ Kern,
                                                         float* __restrict__ out) {
    const int tid  = threadIdx.x;
    const int lane = tid & 63;
    const int w16  = tid >> 6;                 // wave 0..15 = row-within-tile
    const int b    = blockIdx.x;               // uq*32 + hq  (uq-major!)
    const int uq   = b >> 5;                   // 0..7
    const int hq   = b & 31;                   // 0..31
    const int orow = 16 * hq + w16;            // output row 0..511
    const int h    = orow >> 2;                // kernel-grid row
    const int u0   = uq ? (4 * uq + 1) : 0;    // chunk taps: 5,4,4,4,4,4,4,4
    const int nu   = uq ? 4 : 5;

    f2 aL[3][2], aH[3][2];                     // [c][half]: (oj0,oj1)/(oj2,oj3)
#pragma unroll
    for (int c = 0; c < 3; ++c)
#pragma unroll
        for (int hf = 0; hf < 2; ++hf) { aL[c][hf] = (f2)(0.0f); aH[c][hf] = (f2)(0.0f); }

#pragma unroll 1
    for (int t = 0; t < nu; ++t) {
        const int u = u0 + t;
        const size_t krow = (size_t)(u * 33) * KSTR + (size_t)h * NB;
#pragma unroll
        for (int hf = 0; hf < 2; ++hf) {
            const int w = hf * 64 + lane;      // kernel-grid col 0..127
            // 33 taps' weights for (h,w): block-level footprint per tap is
            // 4 rows x 512B = 2KB contiguous -> DRAM/L3-friendly granules
            float wv[33];
#pragma unroll
            for (int v = 0; v < 33; ++v)
                wv[v] = Kern[krow + (size_t)v * KSTR + w];
#pragma unroll
            for (int c = 0; c < 3; ++c) {
                // 36-col fp32 window at pad row orow+u, col 4w (16B aligned)
                const float* ip = gpad + ((size_t)c * PD + orow + u) * PD + 4 * w;
                float wf[36];
#pragma unroll
                for (int j = 0; j < 9; ++j) {
                    const float4 rr = *(const float4*)(ip + 4 * j);
                    wf[4 * j + 0] = rr.x;
                    wf[4 * j + 1] = rr.y;
                    wf[4 * j + 2] = rr.z;
                    wf[4 * j + 3] = rr.w;
                }
                f2 l = aL[c][hf], hh = aH[c][hf];
#pragma unroll
                for (int v = 0; v < 33; ++v) {
                    const f2 w2 = {wv[v], wv[v]};
                    const f2 xl = {wf[v + 0], wf[v + 1]};
                    const f2 xh = {wf[v + 2], wf[v + 3]};
                    l  = xl * w2 + l;          // -> v_pk_fma_f32
                    hh = xh * w2 + hh;
                }
                aL[c][hf] = l; aH[c][hf] = hh;
            }
        }
    }

    // ---- epilogue: 8 u-chunks accumulate into the pad-zeroed output ----
#pragma unroll
    for (int c = 0; c < 3; ++c) {
        float* orow_p = out + ((size_t)c * HH + orow) * WW;
#pragma unroll
        for (int hf = 0; hf < 2; ++hf) {
            float* op = orow_p + 4 * (hf * 64 + lane);
            atomicAdd(op + 0, aL[c][hf].x);
            atomicAdd(op + 1, aL[c][hf].y);
            atomicAdd(op + 2, aH[c][hf].x);
            atomicAdd(op + 3, aH[c][hf].y);
        }
    }
}

// ---------------- fallback (ws too small): naive but correct ----------------
__global__ __launch_bounds__(256) void reblur_naive(const float* __restrict__ img,
                                                    const float* __restrict__ Kern,
                                                    float* __restrict__ out) {
    const int lane = threadIdx.x & 63;
    const int dy   = threadIdx.x >> 6;
    const int c    = blockIdx.x >> 8;
    const int bb   = blockIdx.x & 255;
    const int h    = bb >> 1;
    const int wt   = bb & 1;
    const int wb   = wt * 64 + lane;
    const int y    = 4 * h + dy;

    float acc[4] = {0.f, 0.f, 0.f, 0.f};
    const float* kb = Kern + h * NB + wb;
#pragma unroll 1
    for (int u = 0; u < 33; ++u) {
        const int iy = min(max(y + u - 16, 0), HH - 1);
        float row[36];
#pragma unroll
        for (int e = 0; e < 36; ++e) {
            const int ix = min(max(4 * wb + e - 16, 0), WW - 1);
            row[e]       = img[(c * HH + iy) * WW + ix];
        }
#pragma unroll
        for (int v = 0; v < 33; ++v) {
            const float w = kb[(u * 33 + v) * KSTR];
#pragma unroll
            for (int oj = 0; oj < 4; ++oj)
                acc[oj] = fmaf(row[v + oj], w, acc[oj]);
        }
    }
    float4 o;
    o.x = acc[0]; o.y = acc[1]; o.z = acc[2]; o.w = acc[3];
    *reinterpret_cast<float4*>(out + (size_t)(c * HH + y) * WW + 4 * wb) = o;
}

extern "C" void kernel_launch(void* const* d_in, const int* in_sizes, int n_in,
                              void* d_out, int out_size, void* d_ws, size_t ws_size,
                              hipStream_t stream) {
    const float* img  = (const float*)d_in[0];
    const float* Kern = (const float*)d_in[1];
    float* out        = (float*)d_out;

    if (ws_size >= (size_t)PADN * sizeof(float)) {
        float* gpad = (float*)d_ws;
        pad_f32<<<(PADN + 255) / 256, 256, 0, stream>>>(img, gpad, out);
        reblur_direct<<<256, 1024, 0, stream>>>(gpad, Kern, out);
    } else {
        reblur_naive<<<768, 256, 0, stream>>>(img, Kern, out);
    }
}